// Round 3
// baseline (297.169 us; speedup 1.0000x reference)
//
#include <hip/hip_runtime.h>
#include <hip/hip_bf16.h>

// CRF forward via chunked transfer matrices on MFMA.
// B=2048 blocks x 8 waves; wave w computes T_chunk (32x32) for steps
// [w*64, w*64+64) of its batch in the linear domain (bf16 MFMA, f32 acc),
// renormalized by a power-of-2 every 4 steps. Epilogue composes the 8 chunk
// matrices against the one-hot START vector and applies the STOP transition.

constexpr int SEQ = 512;
constexpr int NTAGS = 32;
constexpr int START_TAG = 30;
constexpr int STOP_TAG = 31;
constexpr float LOG2E = 1.4426950408889634f;
constexpr float LN2 = 0.6931471805599453f;
constexpr int CHUNK = 64;
constexpr int NWAVE = 8;

typedef float f32x16 __attribute__((ext_vector_type(16)));
typedef short bf16x8 __attribute__((ext_vector_type(8)));
typedef int i32x4 __attribute__((ext_vector_type(4)));

#if __has_builtin(__builtin_amdgcn_exp2f)
#define EXP2(x) __builtin_amdgcn_exp2f(x)
#else
#define EXP2(x) exp2f(x)
#endif
#if __has_builtin(__builtin_amdgcn_logf)
#define LOG2(x) __builtin_amdgcn_logf(x)
#else
#define LOG2(x) log2f(x)
#endif

// Pack two f32 -> one dword of 2x bf16 (RTNE) via compiler casts; clang fuses
// the pair into v_cvt_pk_bf16_f32 (m240: scalar casts beat hand-written asm).
static __device__ __forceinline__ int bf16pk(float lo, float hi) {
  union { __hip_bfloat162 v; int i; } u;
  u.v.x = __float2bfloat16(lo);
  u.v.y = __float2bfloat16(hi);
  return u.i;
}

__global__ __launch_bounds__(NWAVE * 64, 4) void crf_fwd_mfma(
    const float* __restrict__ feat, const float* __restrict__ trans,
    float* __restrict__ out) {
  const int tid = threadIdx.x;
  const int w = tid >> 6;    // wave id = chunk id
  const int lane = tid & 63;
  const int h = lane >> 5;   // k-half
  const int mi = lane & 31;  // A-row / B-col / C-col
  const int b = blockIdx.x;

  __shared__ float Tl[NWAVE][32 * 32];  // chunk matrices (transposed+swizzled)
  __shared__ float sig[NWAVE];          // per-chunk log2 scale
  __shared__ float pv[NTAGS];           // composition vector

  // k-index per acc/B slot q (verified C/D map: row=(reg&3)+8*(reg>>2)+4*h)
  int rowq[16];
#pragma unroll
  for (int q = 0; q < 16; ++q) rowq[q] = (q & 3) + 8 * (q >> 2) + 4 * h;

  // ET in the same permuted slot layout so A-slot k matches B-slot k.
  float ETp[16];
#pragma unroll
  for (int q = 0; q < 16; ++q)
    ETp[q] = EXP2(LOG2E * trans[mi * 32 + rowq[q]]);

  // B = identity (bf16, permuted-slot layout)
  int Bw[8];
#pragma unroll
  for (int r = 0; r < 8; ++r) {
    int lo = (rowq[2 * r] == mi) ? 0x3F80 : 0;
    int hi = (rowq[2 * r + 1] == mi) ? 0x3F80 : 0;
    Bw[r] = lo | (hi << 16);
  }

  const f32x16 zero = {};
  f32x16 acc;
  float sigma = 0.0f, nshift = 0.0f;

  const float* Fp = feat + ((size_t)b * SEQ + (size_t)w * CHUNK) * NTAGS + mi;
  float em[8];
#pragma unroll
  for (int u = 0; u < 8; ++u) em[u] = Fp[u * 32];
  Fp += 8 * 32;

  auto step = [&](float emv, float sh) {
    float arg = fminf(fmaf(emv, LOG2E, sh), 120.0f);  // clamp: no inf ever
    float e2 = EXP2(arg);
    int Aw[8];
#pragma unroll
    for (int r = 0; r < 8; ++r)
      Aw[r] = bf16pk(e2 * ETp[2 * r], e2 * ETp[2 * r + 1]);
    bf16x8 A0 = __builtin_bit_cast(bf16x8, (i32x4){Aw[0], Aw[1], Aw[2], Aw[3]});
    bf16x8 A1 = __builtin_bit_cast(bf16x8, (i32x4){Aw[4], Aw[5], Aw[6], Aw[7]});
    bf16x8 B0 = __builtin_bit_cast(bf16x8, (i32x4){Bw[0], Bw[1], Bw[2], Bw[3]});
    bf16x8 B1 = __builtin_bit_cast(bf16x8, (i32x4){Bw[4], Bw[5], Bw[6], Bw[7]});
    f32x16 c0 = __builtin_amdgcn_mfma_f32_32x32x16_bf16(A0, B0, zero, 0, 0, 0);
    acc = __builtin_amdgcn_mfma_f32_32x32x16_bf16(A1, B1, c0, 0, 0, 0);
#pragma unroll
    for (int r = 0; r < 8; ++r) Bw[r] = bf16pk(acc[2 * r], acc[2 * r + 1]);
  };

  auto renorm = [&]() {
    float m = acc[0];
#pragma unroll
    for (int q = 1; q < 16; ++q) m = fmaxf(m, acc[q]);
#pragma unroll
    for (int d = 1; d <= 32; d <<= 1) m = fmaxf(m, __shfl_xor(m, d, 64));
    int eb = (__float_as_int(m) >> 23) & 0xFF;
    sigma += (float)(eb - 127);
    nshift = fminf(fmaxf((float)(127 - eb), -126.0f), 110.0f);
  };

  for (int blk = 0; blk < CHUNK / 8 - 1; ++blk) {
#pragma unroll
    for (int u = 0; u < 8; ++u) {
      step(em[u], (u == 0 || u == 4) ? nshift : 0.0f);
      if (u == 3) renorm();  // renorm every 4 steps
      em[u] = Fp[u * 32];    // prefetch next block
    }
    Fp += 8 * 32;
    renorm();
  }
#pragma unroll
  for (int u = 0; u < 8; ++u) {
    step(em[u], (u == 0 || u == 4) ? nshift : 0.0f);
    if (u == 3) renorm();
  }

  // final normalize so max entry lands in [1,2)
  {
    float m = acc[0];
#pragma unroll
    for (int q = 1; q < 16; ++q) m = fmaxf(m, acc[q]);
#pragma unroll
    for (int d = 1; d <= 32; d <<= 1) m = fmaxf(m, __shfl_xor(m, d, 64));
    int eb = (__float_as_int(m) >> 23) & 0xFF;
    if (eb < 1) eb = 1;
    if (eb > 253) eb = 253;
    sigma += (float)(eb - 127);
    float g = __int_as_float((254 - eb) << 23);  // 2^(127-eb)
#pragma unroll
    for (int q = 0; q < 16; ++q) acc[q] *= g;
  }

  // store T^T with XOR swizzle: phys[col*32 + (row^col)] -> conflict-free
#pragma unroll
  for (int q = 0; q < 16; ++q)
    Tl[w][mi * 32 + (rowq[q] ^ mi)] = acc[q];
  if (lane == 0) sig[w] = sigma;
  __syncthreads();

  if (w == 0) {
    if (h == 0) pv[mi] = (mi == START_TAG) ? 1.0f : 0.0f;
    float v = 0.0f;
    for (int c = 0; c < NWAVE; ++c) {
      v = 0.0f;
#pragma unroll
      for (int u = 0; u < 16; ++u) {
        int j = 16 * h + u;
        v = fmaf(Tl[c][j * 32 + (mi ^ j)], pv[j], v);  // T[mi][j]
      }
      v += __shfl_xor(v, 32, 64);
      if (h == 0) pv[mi] = v;
    }
    float stw = EXP2(LOG2E * trans[STOP_TAG * 32 + mi]);
    float d = v * stw;
#pragma unroll
    for (int dd = 1; dd <= 16; dd <<= 1) d += __shfl_xor(d, dd, 64);
    if (tid == 0) {
      float sg = 0.0f;
      for (int c2 = 0; c2 < NWAVE; ++c2) sg += sig[c2];
      out[b] = LN2 * (LOG2(d) + sg);
    }
  }
}

extern "C" void kernel_launch(void* const* d_in, const int* in_sizes, int n_in,
                              void* d_out, int out_size, void* d_ws,
                              size_t ws_size, hipStream_t stream) {
  const float* feat = (const float*)d_in[0];
  const float* trans = (const float*)d_in[1];
  float* out = (float*)d_out;
  const int B = in_sizes[0] / (SEQ * NTAGS);
  crf_fwd_mfma<<<B, NWAVE * 64, 0, stream>>>(feat, trans, out);
}

// Round 7
// 242.358 us; speedup vs baseline: 1.2262x; 1.2262x over previous
//
#include <hip/hip_runtime.h>

// CRF forward via chunked transfer matrices on MFMA.
// B=2048 blocks x 8 waves; wave w computes T_chunk (32x32) for steps
// [w*64, w*64+64) of its batch in the linear domain (bf16 MFMA, f32 acc),
// renormalized by a power-of-2 every 4 steps. Epilogue composes the 8 chunk
// matrices against the one-hot START vector and applies the STOP transition.
// Round 5/6/7 (two GPUAcquisitionTimeouts; identical resubmit): round-3
// known-good kernel EXCEPT the bf16 pack: software RTNE (~5 inst) ->
// single v_perm_b32 truncation (builtin, no asm).

constexpr int SEQ = 512;
constexpr int NTAGS = 32;
constexpr int START_TAG = 30;
constexpr int STOP_TAG = 31;
constexpr float LOG2E = 1.4426950408889634f;
constexpr float LN2 = 0.6931471805599453f;
constexpr int CHUNK = 64;
constexpr int NWAVE = 8;

typedef float f32x16 __attribute__((ext_vector_type(16)));
typedef short bf16x8 __attribute__((ext_vector_type(8)));
typedef int i32x4 __attribute__((ext_vector_type(4)));

#if __has_builtin(__builtin_amdgcn_exp2f)
#define EXP2(x) __builtin_amdgcn_exp2f(x)
#else
#define EXP2(x) exp2f(x)
#endif
#if __has_builtin(__builtin_amdgcn_logf)
#define LOG2(x) __builtin_amdgcn_logf(x)
#else
#define LOG2(x) log2f(x)
#endif

// Pack two f32 -> dword of 2x bf16 by TRUNCATION, one v_perm_b32:
// out = { hi[31:16], lo[31:16] }. Builtin (compiler-known) -> no asm hazards.
// Truncation of finite nonnegative floats cannot create inf/NaN.
static __device__ __forceinline__ int bf16pk(float lo, float hi) {
  return (int)__builtin_amdgcn_perm(__float_as_uint(hi), __float_as_uint(lo),
                                    0x07060302u);
}

__global__ __launch_bounds__(NWAVE * 64, 4) void crf_fwd_mfma(
    const float* __restrict__ feat, const float* __restrict__ trans,
    float* __restrict__ out) {
  const int tid = threadIdx.x;
  const int w = tid >> 6;    // wave id = chunk id
  const int lane = tid & 63;
  const int h = lane >> 5;   // k-half
  const int mi = lane & 31;  // A-row / B-col / C-col
  const int b = blockIdx.x;

  __shared__ float Tl[NWAVE][32 * 32];  // chunk matrices (transposed+swizzled)
  __shared__ float sig[NWAVE];          // per-chunk log2 scale
  __shared__ float pv[NTAGS];           // composition vector

  // k-index per acc/B slot q (verified C/D map: row=(reg&3)+8*(reg>>2)+4*h)
  int rowq[16];
#pragma unroll
  for (int q = 0; q < 16; ++q) rowq[q] = (q & 3) + 8 * (q >> 2) + 4 * h;

  // ET in the same permuted slot layout so A-slot k matches B-slot k.
  float ETp[16];
#pragma unroll
  for (int q = 0; q < 16; ++q)
    ETp[q] = EXP2(LOG2E * trans[mi * 32 + rowq[q]]);

  // B = identity (bf16, permuted-slot layout)
  int Bw[8];
#pragma unroll
  for (int r = 0; r < 8; ++r) {
    int lo = (rowq[2 * r] == mi) ? 0x3F80 : 0;
    int hi = (rowq[2 * r + 1] == mi) ? 0x3F80 : 0;
    Bw[r] = lo | (hi << 16);
  }

  const f32x16 zero = {};
  f32x16 acc;
  float sigma = 0.0f, nshift = 0.0f;

  const float* Fp = feat + ((size_t)b * SEQ + (size_t)w * CHUNK) * NTAGS + mi;
  float em[8];
#pragma unroll
  for (int u = 0; u < 8; ++u) em[u] = Fp[u * 32];
  Fp += 8 * 32;

  auto step = [&](float emv, float sh) {
    float arg = fminf(fmaf(emv, LOG2E, sh), 120.0f);  // clamp: no inf ever
    float e2 = EXP2(arg);
    int Aw[8];
#pragma unroll
    for (int r = 0; r < 8; ++r)
      Aw[r] = bf16pk(e2 * ETp[2 * r], e2 * ETp[2 * r + 1]);
    bf16x8 A0 = __builtin_bit_cast(bf16x8, (i32x4){Aw[0], Aw[1], Aw[2], Aw[3]});
    bf16x8 A1 = __builtin_bit_cast(bf16x8, (i32x4){Aw[4], Aw[5], Aw[6], Aw[7]});
    bf16x8 B0 = __builtin_bit_cast(bf16x8, (i32x4){Bw[0], Bw[1], Bw[2], Bw[3]});
    bf16x8 B1 = __builtin_bit_cast(bf16x8, (i32x4){Bw[4], Bw[5], Bw[6], Bw[7]});
    f32x16 c0 = __builtin_amdgcn_mfma_f32_32x32x16_bf16(A0, B0, zero, 0, 0, 0);
    acc = __builtin_amdgcn_mfma_f32_32x32x16_bf16(A1, B1, c0, 0, 0, 0);
#pragma unroll
    for (int r = 0; r < 8; ++r) Bw[r] = bf16pk(acc[2 * r], acc[2 * r + 1]);
  };

  auto renorm = [&]() {
    float m = acc[0];
#pragma unroll
    for (int q = 1; q < 16; ++q) m = fmaxf(m, acc[q]);
#pragma unroll
    for (int d = 1; d <= 32; d <<= 1) m = fmaxf(m, __shfl_xor(m, d, 64));
    int eb = (__float_as_int(m) >> 23) & 0xFF;
    sigma += (float)(eb - 127);
    nshift = fminf(fmaxf((float)(127 - eb), -126.0f), 110.0f);
  };

  for (int blk = 0; blk < CHUNK / 8 - 1; ++blk) {
#pragma unroll
    for (int u = 0; u < 8; ++u) {
      step(em[u], (u == 0 || u == 4) ? nshift : 0.0f);
      if (u == 3) renorm();  // renorm every 4 steps
      em[u] = Fp[u * 32];    // prefetch next block
    }
    Fp += 8 * 32;
    renorm();
  }
#pragma unroll
  for (int u = 0; u < 8; ++u) {
    step(em[u], (u == 0 || u == 4) ? nshift : 0.0f);
    if (u == 3) renorm();
  }

  // final normalize so max entry lands in [1,2)
  {
    float m = acc[0];
#pragma unroll
    for (int q = 1; q < 16; ++q) m = fmaxf(m, acc[q]);
#pragma unroll
    for (int d = 1; d <= 32; d <<= 1) m = fmaxf(m, __shfl_xor(m, d, 64));
    int eb = (__float_as_int(m) >> 23) & 0xFF;
    if (eb < 1) eb = 1;
    if (eb > 253) eb = 253;
    sigma += (float)(eb - 127);
    float g = __int_as_float((254 - eb) << 23);  // 2^(127-eb)
#pragma unroll
    for (int q = 0; q < 16; ++q) acc[q] *= g;
  }

  // store T^T with XOR swizzle: phys[col*32 + (row^col)] -> conflict-free
#pragma unroll
  for (int q = 0; q < 16; ++q)
    Tl[w][mi * 32 + (rowq[q] ^ mi)] = acc[q];
  if (lane == 0) sig[w] = sigma;
  __syncthreads();

  if (w == 0) {
    if (h == 0) pv[mi] = (mi == START_TAG) ? 1.0f : 0.0f;
    float v = 0.0f;
    for (int c = 0; c < NWAVE; ++c) {
      v = 0.0f;
#pragma unroll
      for (int u = 0; u < 16; ++u) {
        int j = 16 * h + u;
        v = fmaf(Tl[c][j * 32 + (mi ^ j)], pv[j], v);  // T[mi][j]
      }
      v += __shfl_xor(v, 32, 64);
      if (h == 0) pv[mi] = v;
    }
    float stw = EXP2(LOG2E * trans[STOP_TAG * 32 + mi]);
    float d = v * stw;
#pragma unroll
    for (int dd = 1; dd <= 16; dd <<= 1) d += __shfl_xor(d, dd, 64);
    if (tid == 0) {
      float sg = 0.0f;
      for (int c2 = 0; c2 < NWAVE; ++c2) sg += sig[c2];
      out[b] = LN2 * (LOG2(d) + sg);
    }
  }
}

extern "C" void kernel_launch(void* const* d_in, const int* in_sizes, int n_in,
                              void* d_out, int out_size, void* d_ws,
                              size_t ws_size, hipStream_t stream) {
  const float* feat = (const float*)d_in[0];
  const float* trans = (const float*)d_in[1];
  float* out = (float*)d_out;
  const int B = in_sizes[0] / (SEQ * NTAGS);
  crf_fwd_mfma<<<B, NWAVE * 64, 0, stream>>>(feat, trans, out);
}